// Round 4
// baseline (2037.020 us; speedup 1.0000x reference)
//
#include <hip/hip_runtime.h>
#include <math.h>

// EdgeEvidenceHead — round 4: node-factored projections + 2 blocks/CU.
//
// W1 rows [0,128)/[128,256) act linearly on z_u/z_v -> precompute per-node
// P1 = z@W1[0:128], P2 = z@W1[128:256] (fp32, split-bf16 3-product GEMM).
// Edge kernel: acc init = gather(P1[u]) + gather(P2[v]); K-loop only covers
// abs(128) + prod(128) + tail(7) = 9 chunks of 32. Features built in-register
// at gather time (full fp32 inputs), W chunks reg-staged (T14) into a single
// 32KB LDS buffer. LDS 70.9KB -> 2 blocks/CU. Fallback to round-3 kernel if
// ws_size can't hold the 205MB P tables.

typedef __attribute__((ext_vector_type(8))) short short8;
typedef __attribute__((ext_vector_type(4))) float f32x4;
typedef unsigned int u32;
typedef unsigned short u16;

#define NEDGES  500000
#define NNODES  100000
#define WCHUNK  32768                    // one K32 W-image chunk: hi 16KB + lo 16KB
#define NCH     17                       // 544 = 17*32 k-rows (519 padded)
#define NBP     1563                     // ceil(100000/64) node blocks per table
#define WS_WIMG 557056ull                // 17*32768
#define P_ELEMS 25600000ull              // floats per P table
#define WS_NEED (WS_WIMG + 2ull * P_ELEMS * 4ull)

__device__ __forceinline__ u16 f2bf(float f) {               // RTN-even bf16
    u32 u = __float_as_uint(f);
    return (u16)((u + 0x7fffu + ((u >> 16) & 1u)) >> 16);
}
__device__ __forceinline__ float bf2f(u16 h) { return __uint_as_float(((u32)h) << 16); }
__device__ __forceinline__ float softplus_f(float x) {
    return fmaxf(x, 0.0f) + log1pf(expf(-fabsf(x)));
}
// W image swizzle (absolute-address triangular XOR: b4^=b6, b5^=b7, b6^=b8)
__device__ __forceinline__ int swz64(int r, int col) { return (r * 64 + col) ^ ((r & 7) << 4); }
// edge feature buffer: [32 e][288 k] bf16, row stride 576B; 2-bit key keeps col^key < 576
__device__ __forceinline__ int swzE(int e, int col)  { return e * 576 + (col ^ ((e & 3) << 4)); }
// prep_p z buffer: [64 n][128 k] bf16, row stride 256B; triangular absolute XOR
__device__ __forceinline__ int swzZ(int n, int col)  { return (n * 256 + col) ^ ((n & 7) << 4); }

__device__ __forceinline__ void stage16(const char* g, char* l) {
    __builtin_amdgcn_global_load_lds((const __attribute__((address_space(1))) u32*)g,
                                     (__attribute__((address_space(3))) u32*)l, 16, 0, 0);
}
__device__ __forceinline__ void split8(const float4& A, const float4& B, short8& h, short8& l) {
    const float v[8] = {A.x, A.y, A.z, A.w, B.x, B.y, B.z, B.w};
    #pragma unroll
    for (int j = 0; j < 8; ++j) {
        const u16 hh = f2bf(v[j]);
        h[j] = (short)hh;
        l[j] = (short)f2bf(v[j] - bf2f(hh));
    }
}

// ---- prep: W1[k][m] -> 17 per-chunk pre-swizzled LDS images (hi16KB|lo16KB) ----
__global__ void prep_w1t(const float* __restrict__ W1, u16* __restrict__ ws) {
    const int k = blockIdx.x;          // 0..543
    const int m = threadIdx.x;         // 0..255
    const float v = (k < 519) ? W1[k * 256 + m] : 0.0f;
    const u16 h = f2bf(v);
    const u16 l = f2bf(v - bf2f(h));
    const int kc = k >> 5, kl = k & 31;
    const int P = ((m * 64 + (kl >> 3) * 16) ^ ((m & 7) << 4)) + (kl & 7) * 2;
    u16* base = ws + (size_t)kc * (WCHUNK / 2);
    base[P / 2] = h;
    base[(16384 + P) / 2] = l;
}

// ---- prep_p: P[tab][n][m] = sum_k z[n][k] * W1[tab*128+k][m]  (split-bf16 x3) ----
__global__ __launch_bounds__(256)
void prep_p(const float* __restrict__ z, const u16* __restrict__ wimg,
            float* __restrict__ P)
{
    __shared__ alignas(16) char lds[65536];    // ZH 16K | ZL 16K | W 32K
    char* ZH = lds;
    char* ZL = lds + 16384;
    char* WB = lds + 32768;

    const int t = threadIdx.x;
    const int lane = t & 63, wv = t >> 6;
    int bb = blockIdx.x, tab = 0;
    if (bb >= NBP) { tab = 1; bb -= NBP; }
    const int n0 = bb * 64;

    // reg-stage W chunk 0 of this table
    float4 wreg[8];
    {
        const float4* src = (const float4*)((const char*)wimg + (size_t)(tab * 4) * WCHUNK + t * 128);
        #pragma unroll
        for (int i = 0; i < 8; ++i) wreg[i] = src[i];
    }
    // load + split 32 z values (node = n0 + t/4, seg = t%4)
    {
        int node = n0 + (t >> 2);
        if (node >= NNODES) node = NNODES - 1;
        const int seg = t & 3;
        const float* zp = z + (size_t)node * 128 + seg * 32;
        const int r = t >> 2;
        #pragma unroll
        for (int j = 0; j < 4; ++j) {
            const float4 a = *(const float4*)(zp + j * 8);
            const float4 b = *(const float4*)(zp + j * 8 + 4);
            short8 h8, l8;
            split8(a, b, h8, l8);
            const int off = swzZ(r, seg * 64 + j * 16);
            *(short8*)(ZH + off) = h8;
            *(short8*)(ZL + off) = l8;
        }
    }
    {   // write W chunk 0
        float4* dst = (float4*)(WB + t * 128);
        #pragma unroll
        for (int i = 0; i < 8; ++i) dst[i] = wreg[i];
    }

    const f32x4 vz = {0.f, 0.f, 0.f, 0.f};
    f32x4 acc[4][4];
    #pragma unroll
    for (int mf = 0; mf < 4; ++mf)
        #pragma unroll
        for (int nf = 0; nf < 4; ++nf) acc[mf][nf] = vz;

    const int el = lane & 15, kq = lane >> 4;
    __syncthreads();

    for (int kc = 0; kc < 4; ++kc) {
        if (kc < 3) {
            const float4* src = (const float4*)((const char*)wimg + (size_t)(tab * 4 + kc + 1) * WCHUNK + t * 128);
            #pragma unroll
            for (int i = 0; i < 8; ++i) wreg[i] = src[i];
        }
        short8 Bh[4], Bl[4];
        #pragma unroll
        for (int nf = 0; nf < 4; ++nf) {
            const int off = swzZ(nf * 16 + el, kc * 64 + kq * 16);
            Bh[nf] = *(const short8*)(ZH + off);
            Bl[nf] = *(const short8*)(ZL + off);
        }
        #pragma unroll
        for (int mf = 0; mf < 4; ++mf) {
            const int offA = swz64(wv * 64 + mf * 16 + el, kq * 16);
            const short8 Ah = *(const short8*)(WB + offA);
            const short8 Al = *(const short8*)(WB + 16384 + offA);
            #pragma unroll
            for (int nf = 0; nf < 4; ++nf) {
                acc[mf][nf] = __builtin_amdgcn_mfma_f32_16x16x32_bf16(Ah, Bh[nf], acc[mf][nf], 0, 0, 0);
                acc[mf][nf] = __builtin_amdgcn_mfma_f32_16x16x32_bf16(Al, Bh[nf], acc[mf][nf], 0, 0, 0);
                acc[mf][nf] = __builtin_amdgcn_mfma_f32_16x16x32_bf16(Ah, Bl[nf], acc[mf][nf], 0, 0, 0);
            }
        }
        __syncthreads();
        if (kc < 3) {
            float4* dst = (float4*)(WB + t * 128);
            #pragma unroll
            for (int i = 0; i < 8; ++i) dst[i] = wreg[i];
            __syncthreads();
        }
    }

    // store: m = wv*64+mf*16+kq*4+r, node-local n = nf*16+el
    #pragma unroll
    for (int nf = 0; nf < 4; ++nf) {
        const int node = n0 + nf * 16 + el;
        if (node < NNODES) {
            #pragma unroll
            for (int mf = 0; mf < 4; ++mf) {
                float4 v;
                v.x = acc[mf][nf][0]; v.y = acc[mf][nf][1];
                v.z = acc[mf][nf][2]; v.w = acc[mf][nf][3];
                *(float4*)(P + (size_t)tab * P_ELEMS + (size_t)node * 256 + wv * 64 + mf * 16 + kq * 4) = v;
            }
        }
    }
}

// ---- main edge kernel (P path): 32 edges/block, 9 K-chunks, 70.9KB LDS ----
#define OFF_FH   0        // feature hi  [32][288] bf16  (18432 B)
#define OFF_FL   18432    // feature lo                   (18432 B)
#define OFF_W    36864    // W chunk single buffer        (32768 B)
#define OFF_SU   69632
#define OFF_SV   69760
#define OFF_SRED 69888    // [4 wv][32 e] float2          (1024 B)
#define LDS2_SZ  70912

__global__ __launch_bounds__(256, 2)
void edge_mfma_p(const float* __restrict__ z,
                 const int*   __restrict__ eidx,
                 const float* __restrict__ extra,
                 const float* __restrict__ b1,
                 const float* __restrict__ W2,
                 const float* __restrict__ b2,
                 const u16*   __restrict__ wimg,
                 const float* __restrict__ P,
                 float* __restrict__ out)
{
    __shared__ alignas(16) char lds[LDS2_SZ];
    char* FH = lds + OFF_FH;
    char* FL = lds + OFF_FL;
    char* WB = lds + OFF_W;

    const int t = threadIdx.x;
    const int lane = t & 63, wv = t >> 6;
    const int e0 = blockIdx.x * 32;
    const int el = lane & 15, kq = lane >> 4;

    // reg-stage W chunk 0 (global image chunk 8) — issue first, longest latency
    float4 wreg[8];
    {
        const float4* src = (const float4*)((const char*)wimg + (size_t)8 * WCHUNK + t * 128);
        #pragma unroll
        for (int i = 0; i < 8; ++i) wreg[i] = src[i];
    }

    if (t < 32)       *(int*)(lds + OFF_SU + t * 4) = eidx[e0 + t];
    else if (t < 64)  *(int*)(lds + OFF_SV + (t - 32) * 4) = eidx[NEDGES + e0 + (t - 32)];
    __syncthreads();

    const int* su = (const int*)(lds + OFF_SU);
    const int* sv = (const int*)(lds + OFF_SV);

    // ---- P gathers (coalesced 64B segments; consumed at acc init below) ----
    float4 p1v[2][4], p2v[2][4];
    #pragma unroll
    for (int nf = 0; nf < 2; ++nf) {
        const float* r1 = P + (size_t)su[nf * 16 + el] * 256 + wv * 64 + kq * 4;
        const float* r2 = P + P_ELEMS + (size_t)sv[nf * 16 + el] * 256 + wv * 64 + kq * 4;
        #pragma unroll
        for (int mf = 0; mf < 4; ++mf) {
            p1v[nf][mf] = *(const float4*)(r1 + mf * 16);
            p2v[nf][mf] = *(const float4*)(r2 + mf * 16);
        }
    }

    // ---- gather z, build abs/prod (+tail) features in-register, write LDS ----
    {
        const int e = t >> 3, oct = t & 7;       // e 0..31, 16-k slice per thread
        const float* pu = z + (size_t)su[e] * 128 + oct * 16;
        const float* pv = z + (size_t)sv[e] * 128 + oct * 16;
        float uf[16], vf[16];
        #pragma unroll
        for (int j = 0; j < 4; ++j) {
            *(float4*)&uf[j * 4] = *(const float4*)(pu + j * 4);
            *(float4*)&vf[j * 4] = *(const float4*)(pv + j * 4);
        }
        float d = 0.f, nu = 0.f, nv = 0.f;
        #pragma unroll
        for (int j = 0; j < 16; ++j) {
            d  = fmaf(uf[j], vf[j], d);
            nu = fmaf(uf[j], uf[j], nu);
            nv = fmaf(vf[j], vf[j], nv);
        }
        #pragma unroll
        for (int half = 0; half < 2; ++half) {
            short8 ah, al, ph, pl;
            #pragma unroll
            for (int j = 0; j < 8; ++j) {
                const float ab = fabsf(uf[half * 8 + j] - vf[half * 8 + j]);
                const float pr = uf[half * 8 + j] * vf[half * 8 + j];
                u16 h = f2bf(ab);
                ah[j] = (short)h; al[j] = (short)f2bf(ab - bf2f(h));
                h = f2bf(pr);
                ph[j] = (short)h; pl[j] = (short)f2bf(pr - bf2f(h));
            }
            const int ca = oct * 32 + half * 16;        // abs k in [0,128)
            *(short8*)(FH + swzE(e, ca)) = ah;
            *(short8*)(FL + swzE(e, ca)) = al;
            *(short8*)(FH + swzE(e, 256 + ca)) = ph;    // prod k in [128,256)
            *(short8*)(FL + swzE(e, 256 + ca)) = pl;
        }
        // 8-lane reduce (lanes e*8..e*8+7 hold same edge)
        d  += __shfl_xor(d, 1);  d  += __shfl_xor(d, 2);  d  += __shfl_xor(d, 4);
        nu += __shfl_xor(nu, 1); nu += __shfl_xor(nu, 2); nu += __shfl_xor(nu, 4);
        nv += __shfl_xor(nv, 1); nv += __shfl_xor(nv, 2); nv += __shfl_xor(nv, 4);
        if (oct == 0) {           // tail row: dot, cos, extra[5], 0 | zeros
            const float nn = fmaxf(sqrtf(nu), 1e-12f) * fmaxf(sqrtf(nv), 1e-12f);
            float vals[8];
            vals[0] = d;
            vals[1] = d / nn;
            #pragma unroll
            for (int j = 0; j < 5; ++j) vals[2 + j] = extra[(size_t)(e0 + e) * 5 + j];
            vals[7] = 0.0f;
            short8 vh, vl;
            #pragma unroll
            for (int j = 0; j < 8; ++j) {
                const u16 h = f2bf(vals[j]);
                vh[j] = (short)h; vl[j] = (short)f2bf(vals[j] - bf2f(h));
            }
            const short8 zz = {0, 0, 0, 0, 0, 0, 0, 0};
            *(short8*)(FH + swzE(e, 512)) = vh;  *(short8*)(FL + swzE(e, 512)) = vl;
            *(short8*)(FH + swzE(e, 528)) = zz;  *(short8*)(FL + swzE(e, 528)) = zz;
        } else if (oct == 1) {
            const short8 zz = {0, 0, 0, 0, 0, 0, 0, 0};
            *(short8*)(FH + swzE(e, 544)) = zz;  *(short8*)(FL + swzE(e, 544)) = zz;
            *(short8*)(FH + swzE(e, 560)) = zz;  *(short8*)(FL + swzE(e, 560)) = zz;
        }
    }
    {   // write W chunk 0 to LDS
        float4* dst = (float4*)(WB + t * 128);
        #pragma unroll
        for (int i = 0; i < 8; ++i) dst[i] = wreg[i];
    }

    // acc init = P1[u] + P2[v]  (replaces the factored-out z chunks)
    f32x4 acc[4][2];
    #pragma unroll
    for (int mf = 0; mf < 4; ++mf)
        #pragma unroll
        for (int nf = 0; nf < 2; ++nf) {
            f32x4 a;
            a[0] = p1v[nf][mf].x + p2v[nf][mf].x;
            a[1] = p1v[nf][mf].y + p2v[nf][mf].y;
            a[2] = p1v[nf][mf].z + p2v[nf][mf].z;
            a[3] = p1v[nf][mf].w + p2v[nf][mf].w;
            acc[mf][nf] = a;
        }
    __syncthreads();

    // ---- K loop: 9 chunks (abs 4, prod 4, tail 1), W reg-staged 1 ahead ----
    for (int kc = 0; kc < 9; ++kc) {
        float4 wnext[8];
        if (kc < 8) {
            const float4* src = (const float4*)((const char*)wimg + (size_t)(9 + kc) * WCHUNK + t * 128);
            #pragma unroll
            for (int i = 0; i < 8; ++i) wnext[i] = src[i];
        }
        short8 Bh[2], Bl[2];
        #pragma unroll
        for (int nf = 0; nf < 2; ++nf) {
            const int off = swzE(nf * 16 + el, kc * 64 + kq * 16);
            Bh[nf] = *(const short8*)(FH + off);
            Bl[nf] = *(const short8*)(FL + off);
        }
        #pragma unroll
        for (int mf = 0; mf < 4; ++mf) {
            const int offA = swz64(wv * 64 + mf * 16 + el, kq * 16);
            const short8 Ah = *(const short8*)(WB + offA);
            const short8 Al = *(const short8*)(WB + 16384 + offA);
            #pragma unroll
            for (int nf = 0; nf < 2; ++nf) {
                acc[mf][nf] = __builtin_amdgcn_mfma_f32_16x16x32_bf16(Ah, Bh[nf], acc[mf][nf], 0, 0, 0);
                acc[mf][nf] = __builtin_amdgcn_mfma_f32_16x16x32_bf16(Al, Bh[nf], acc[mf][nf], 0, 0, 0);
                acc[mf][nf] = __builtin_amdgcn_mfma_f32_16x16x32_bf16(Ah, Bl[nf], acc[mf][nf], 0, 0, 0);
            }
        }
        __syncthreads();
        if (kc < 8) {
            float4* dst = (float4*)(WB + t * 128);
            #pragma unroll
            for (int i = 0; i < 8; ++i) dst[i] = wnext[i];
            __syncthreads();
        }
    }

    // ---- epilogue: bias+ReLU, GEMM2 (256->2), softplus ----
    float b1r[4][4], w20[4][4], w21[4][4];
    #pragma unroll
    for (int mf = 0; mf < 4; ++mf) {
        const int mb = wv * 64 + mf * 16 + kq * 4;
        const float4 bv = *(const float4*)&b1[mb];
        b1r[mf][0] = bv.x; b1r[mf][1] = bv.y; b1r[mf][2] = bv.z; b1r[mf][3] = bv.w;
        #pragma unroll
        for (int r = 0; r < 4; ++r) {
            w20[mf][r] = W2[2 * (mb + r)];
            w21[mf][r] = W2[2 * (mb + r) + 1];
        }
    }
    #pragma unroll
    for (int nf = 0; nf < 2; ++nf) {
        float p0 = 0.f, p1 = 0.f;
        #pragma unroll
        for (int mf = 0; mf < 4; ++mf)
            #pragma unroll
            for (int r = 0; r < 4; ++r) {
                const float h = fmaxf(acc[mf][nf][r] + b1r[mf][r], 0.0f);
                p0 = fmaf(h, w20[mf][r], p0);
                p1 = fmaf(h, w21[mf][r], p1);
            }
        p0 += __shfl_xor(p0, 16); p0 += __shfl_xor(p0, 32);
        p1 += __shfl_xor(p1, 16); p1 += __shfl_xor(p1, 32);
        if (kq == 0)
            *(float2*)(lds + OFF_SRED + (wv * 32 + nf * 16 + el) * 8) = make_float2(p0, p1);
    }
    __syncthreads();
    if (t < 32) {
        float s0 = b2[0], s1 = b2[1];
        #pragma unroll
        for (int w = 0; w < 4; ++w) {
            const float2 pr = *(const float2*)(lds + OFF_SRED + (w * 32 + t) * 8);
            s0 += pr.x; s1 += pr.y;
        }
        out[2 * (size_t)(e0 + t) + 0] = softplus_f(s0);
        out[2 * (size_t)(e0 + t) + 1] = softplus_f(s1);
    }
}

// ================= fallback: round-3 kernel (proven, 736us) =================
#define FB_FHI  0
#define FB_FLO  32768
#define FB_W    65536
#define FB_FC   131072
#define FB_SU   147456
#define FB_SV   147712
#define FB_SDOT 147968
#define FB_SCOS 148224
#define FB_SRED 148480
#define FB_SZ   150528
__device__ __forceinline__ int swzF(int e, int col)  { return (e * 512 + col) ^ ((e & 7) << 4); }
__device__ __forceinline__ void pacc(const float4& a, const float4& c, float& d, float& nu, float& nv) {
    d  = fmaf(a.x, c.x, d);  d  = fmaf(a.y, c.y, d);  d  = fmaf(a.z, c.z, d);  d  = fmaf(a.w, c.w, d);
    nu = fmaf(a.x, a.x, nu); nu = fmaf(a.y, a.y, nu); nu = fmaf(a.z, a.z, nu); nu = fmaf(a.w, a.w, nu);
    nv = fmaf(c.x, c.x, nv); nv = fmaf(c.y, c.y, nv); nv = fmaf(c.z, c.z, nv); nv = fmaf(c.w, c.w, nv);
}
__global__ __launch_bounds__(256)
void edge_mfma_fb(const float* __restrict__ z, const int* __restrict__ eidx,
                  const float* __restrict__ extra, const float* __restrict__ b1,
                  const float* __restrict__ W2, const float* __restrict__ b2,
                  const u16* __restrict__ ws, float* __restrict__ out)
{
    __shared__ alignas(16) char lds[FB_SZ];
    const int t = threadIdx.x, lane = t & 63, wv = t >> 6;
    const int e0 = blockIdx.x * 64;
    {
        const char* src = (const char*)ws + (size_t)wv * 8192 + lane * 16;
        char* dst = lds + FB_W + wv * 8192;
        #pragma unroll
        for (int i = 0; i < 8; ++i) stage16(src + i * 1024, dst + i * 1024);
    }
    {
        int g = e0 + (t & 63);
        if (g >= NEDGES) g = NEDGES - 1;
        if (t < 64)       *(int*)(lds + FB_SU + (t & 63) * 4) = eidx[g];
        else if (t < 128) *(int*)(lds + FB_SV + (t & 63) * 4) = eidx[NEDGES + g];
    }
    __syncthreads();
    {
        const int* su = (const int*)(lds + FB_SU);
        const int* sv = (const int*)(lds + FB_SV);
        #pragma unroll
        for (int r = 0; r < 2; ++r) {
            const int e = wv * 8 + r * 32 + (lane & 7);
            const int oct = lane >> 3;
            const float* pu = z + (size_t)su[e] * 128 + oct * 16;
            const float* pv = z + (size_t)sv[e] * 128 + oct * 16;
            const float4 a0 = *(const float4*)(pu + 0),  a1 = *(const float4*)(pu + 4);
            const float4 a2 = *(const float4*)(pu + 8),  a3 = *(const float4*)(pu + 12);
            const float4 c0 = *(const float4*)(pv + 0),  c1 = *(const float4*)(pv + 4);
            const float4 c2 = *(const float4*)(pv + 8),  c3 = *(const float4*)(pv + 12);
            float d = 0.f, nu = 0.f, nv = 0.f;
            pacc(a0, c0, d, nu, nv); pacc(a1, c1, d, nu, nv);
            pacc(a2, c2, d, nu, nv); pacc(a3, c3, d, nu, nv);
            short8 h8, l8;
            split8(a0, a1, h8, l8);
            *(short8*)(lds + FB_FHI + swzF(e, oct * 32)) = h8;
            *(short8*)(lds + FB_FLO + swzF(e, oct * 32)) = l8;
            split8(a2, a3, h8, l8);
            *(short8*)(lds + FB_FHI + swzF(e, oct * 32 + 16)) = h8;
            *(short8*)(lds + FB_FLO + swzF(e, oct * 32 + 16)) = l8;
            split8(c0, c1, h8, l8);
            *(short8*)(lds + FB_FHI + swzF(e, 256 + oct * 32)) = h8;
            *(short8*)(lds + FB_FLO + swzF(e, 256 + oct * 32)) = l8;
            split8(c2, c3, h8, l8);
            *(short8*)(lds + FB_FHI + swzF(e, 256 + oct * 32 + 16)) = h8;
            *(short8*)(lds + FB_FLO + swzF(e, 256 + oct * 32 + 16)) = l8;
            d  += __shfl_xor(d, 8);  d  += __shfl_xor(d, 16);  d  += __shfl_xor(d, 32);
            nu += __shfl_xor(nu, 8); nu += __shfl_xor(nu, 16); nu += __shfl_xor(nu, 32);
            nv += __shfl_xor(nv, 8); nv += __shfl_xor(nv, 16); nv += __shfl_xor(nv, 32);
            if ((lane >> 3) == 0) {
                *(float*)(lds + FB_SDOT + e * 4) = d;
                const float nn = fmaxf(sqrtf(nu), 1e-12f) * fmaxf(sqrtf(nv), 1e-12f);
                *(float*)(lds + FB_SCOS + e * 4) = d / nn;
            }
        }
    }
    __syncthreads();
    const f32x4 vzero = {0.f, 0.f, 0.f, 0.f};
    f32x4 acc[4][4];
    #pragma unroll
    for (int mf = 0; mf < 4; ++mf)
        #pragma unroll
        for (int nf = 0; nf < 4; ++nf) acc[mf][nf] = vzero;
    const int el = lane & 15, kq = lane >> 4;
    for (int kc = 0; kc < NCH; ++kc) {
        if (kc < NCH - 1) {
            const char* src = (const char*)ws + (size_t)(kc + 1) * WCHUNK + wv * 8192 + lane * 16;
            char* dst = lds + FB_W + ((kc + 1) & 1) * WCHUNK + wv * 8192;
            #pragma unroll
            for (int i = 0; i < 8; ++i) stage16(src + i * 1024, dst + i * 1024);
        }
        if (kc >= 7 && kc < 15) {
            const int kc1 = kc + 1;
            const int eL = (t & 15), kh = (t >> 4) & 3, eh = t >> 6;
            const int e = eh * 16 + eL;
            const int colu = (kc1 & 3) * 64 + kh * 16;
            const short8 uh = *(const short8*)(lds + FB_FHI + swzF(e, colu));
            const short8 ul = *(const short8*)(lds + FB_FLO + swzF(e, colu));
            const short8 vh = *(const short8*)(lds + FB_FHI + swzF(e, 256 + colu));
            const short8 vl = *(const short8*)(lds + FB_FLO + swzF(e, 256 + colu));
            const bool isabs = (kc1 < 12);
            short8 oh, ol;
            #pragma unroll
            for (int j = 0; j < 8; ++j) {
                const float u = bf2f((u16)uh[j]) + bf2f((u16)ul[j]);
                const float v = bf2f((u16)vh[j]) + bf2f((u16)vl[j]);
                const float x = isabs ? fabsf(u - v) : (u * v);
                const u16 hh = f2bf(x);
                oh[j] = (short)hh;
                ol[j] = (short)f2bf(x - bf2f(hh));
            }
            char* fcb = lds + FB_FC + (kc1 & 1) * 8192;
            *(short8*)(fcb + swz64(e, kh * 16)) = oh;
            *(short8*)(fcb + 4096 + swz64(e, kh * 16)) = ol;
        } else if (kc == 15) {
            if (t < 64) {
                const int e = t;
                int g = e0 + e; if (g >= NEDGES) g = NEDGES - 1;
                float vals[8];
                vals[0] = *(const float*)(lds + FB_SDOT + e * 4);
                vals[1] = *(const float*)(lds + FB_SCOS + e * 4);
                #pragma unroll
                for (int j = 0; j < 5; ++j) vals[2 + j] = extra[(size_t)g * 5 + j];
                vals[7] = 0.0f;
                short8 oh, ol;
                #pragma unroll
                for (int j = 0; j < 8; ++j) {
                    const u16 hh = f2bf(vals[j]);
                    oh[j] = (short)hh;
                    ol[j] = (short)f2bf(vals[j] - bf2f(hh));
                }
                char* fcb = lds + FB_FC;
                *(short8*)(fcb + swz64(e, 0)) = oh;
                *(short8*)(fcb + 4096 + swz64(e, 0)) = ol;
                const short8 zz = {0,0,0,0,0,0,0,0};
                #pragma unroll
                for (int c = 16; c < 64; c += 16) {
                    *(short8*)(fcb + swz64(e, c)) = zz;
                    *(short8*)(fcb + 4096 + swz64(e, c)) = zz;
                }
            }
        }
        short8 Bh[4], Bl[4];
        if (kc < 8) {
            const int colb = kc * 64 + kq * 16;
            #pragma unroll
            for (int nf = 0; nf < 4; ++nf) {
                const int off = swzF(nf * 16 + el, colb);
                Bh[nf] = *(const short8*)(lds + FB_FHI + off);
                Bl[nf] = *(const short8*)(lds + FB_FLO + off);
            }
        } else {
            const char* fcb = lds + FB_FC + (kc & 1) * 8192;
            #pragma unroll
            for (int nf = 0; nf < 4; ++nf) {
                const int off = swz64(nf * 16 + el, kq * 16);
                Bh[nf] = *(const short8*)(fcb + off);
                Bl[nf] = *(const short8*)(fcb + 4096 + off);
            }
        }
        const char* wb = lds + FB_W + (kc & 1) * WCHUNK;
        #pragma unroll
        for (int mf = 0; mf < 4; ++mf) {
            const int offA = swz64(wv * 64 + mf * 16 + el, kq * 16);
            const short8 Ah = *(const short8*)(wb + offA);
            const short8 Al = *(const short8*)(wb + 16384 + offA);
            #pragma unroll
            for (int nf = 0; nf < 4; ++nf) {
                acc[mf][nf] = __builtin_amdgcn_mfma_f32_16x16x32_bf16(Ah, Bh[nf], acc[mf][nf], 0, 0, 0);
                acc[mf][nf] = __builtin_amdgcn_mfma_f32_16x16x32_bf16(Al, Bh[nf], acc[mf][nf], 0, 0, 0);
                acc[mf][nf] = __builtin_amdgcn_mfma_f32_16x16x32_bf16(Ah, Bl[nf], acc[mf][nf], 0, 0, 0);
            }
        }
        __syncthreads();
    }
    float b1r[4][4], w20[4][4], w21[4][4];
    #pragma unroll
    for (int mf = 0; mf < 4; ++mf) {
        const int mb = wv * 64 + mf * 16 + kq * 4;
        const float4 bv = *(const float4*)&b1[mb];
        b1r[mf][0] = bv.x; b1r[mf][1] = bv.y; b1r[mf][2] = bv.z; b1r[mf][3] = bv.w;
        #pragma unroll
        for (int r = 0; r < 4; ++r) {
            w20[mf][r] = W2[2 * (mb + r)];
            w21[mf][r] = W2[2 * (mb + r) + 1];
        }
    }
    #pragma unroll
    for (int nf = 0; nf < 4; ++nf) {
        float p0 = 0.f, p1 = 0.f;
        #pragma unroll
        for (int mf = 0; mf < 4; ++mf)
            #pragma unroll
            for (int r = 0; r < 4; ++r) {
                const float h = fmaxf(acc[mf][nf][r] + b1r[mf][r], 0.0f);
                p0 = fmaf(h, w20[mf][r], p0);
                p1 = fmaf(h, w21[mf][r], p1);
            }
        p0 += __shfl_xor(p0, 16); p0 += __shfl_xor(p0, 32);
        p1 += __shfl_xor(p1, 16); p1 += __shfl_xor(p1, 32);
        if (kq == 0)
            *(float2*)(lds + FB_SRED + (wv * 64 + nf * 16 + el) * 8) = make_float2(p0, p1);
    }
    __syncthreads();
    if (t < 64) {
        float s0 = b2[0], s1 = b2[1];
        #pragma unroll
        for (int w = 0; w < 4; ++w) {
            const float2 pr = *(const float2*)(lds + FB_SRED + (w * 64 + t) * 8);
            s0 += pr.x; s1 += pr.y;
        }
        const int g = e0 + t;
        if (g < NEDGES) {
            out[2 * (size_t)g + 0] = softplus_f(s0);
            out[2 * (size_t)g + 1] = softplus_f(s1);
        }
    }
}

extern "C" void kernel_launch(void* const* d_in, const int* in_sizes, int n_in,
                              void* d_out, int out_size, void* d_ws, size_t ws_size,
                              hipStream_t stream) {
    const float* zp    = (const float*)d_in[0];
    const int*   eidx  = (const int*)  d_in[1];
    const float* extra = (const float*)d_in[2];
    const float* W1    = (const float*)d_in[3];
    const float* b1    = (const float*)d_in[4];
    const float* W2    = (const float*)d_in[5];
    const float* b2    = (const float*)d_in[6];
    float* out = (float*)d_out;
    u16* ws = (u16*)d_ws;

    prep_w1t<<<dim3(NCH * 32), dim3(256), 0, stream>>>(W1, ws);   // 544 k-rows

    if (ws_size >= WS_NEED) {
        float* P = (float*)((char*)d_ws + WS_WIMG);
        prep_p<<<dim3(2 * NBP), dim3(256), 0, stream>>>(zp, ws, P);
        edge_mfma_p<<<dim3(NEDGES / 32), dim3(256), 0, stream>>>(
            zp, eidx, extra, b1, W2, b2, ws, P, out);
    } else {
        edge_mfma_fb<<<dim3((NEDGES + 63) / 64), dim3(256), 0, stream>>>(
            zp, eidx, extra, b1, W2, b2, ws, out);
    }
}

// Round 7
// 573.716 us; speedup vs baseline: 3.5506x; 3.5506x over previous
//
#include <hip/hip_runtime.h>
#include <math.h>

// EdgeEvidenceHead — round 7 (= round 6 resubmitted; GPU timeout, no data).
//
// Self-contained split-bf16 MFMA edge kernel.
// Round-5 post-mortem: logic verified correct (first call passed, absmax
// 0.0078) but post-timing re-validation diverged (absmax 0.84 = dropped-
// contribution signature) with 205MB of cross-kernel P state in d_ws.
// This round stays in the proven-stable class (only the 557KB W image in ws,
// single edge kernel, K=544 per edge) while keeping the diagnosed perf fixes:
// no address-taken arrays (round-4 scratch bug), fragment-ordered W image read
// per-lane from L2 (no W LDS, no K-loop barriers), 2 blocks/CU.
//
// Numerics: split-bf16 (x = hi + lo), A*B ~= Ah*Bh + Al*Bh + Ah*Bl (~fp32).

typedef __attribute__((ext_vector_type(8))) short short8;
typedef __attribute__((ext_vector_type(4))) float f32x4;
typedef unsigned int u32;
typedef unsigned short u16;

#define NEDGES 500000
#define NCH    17                      // 544 = 17*32 k-rows (519 zero-padded)

__device__ __forceinline__ u16 f2bf(float f) {               // RTNE bf16
    u32 u = __float_as_uint(f);
    return (u16)((u + 0x7fffu + ((u >> 16) & 1u)) >> 16);
}
__device__ __forceinline__ float bf2f(u16 h) { return __uint_as_float(((u32)h) << 16); }
__device__ __forceinline__ float softplus_f(float x) {
    return fmaxf(x, 0.0f) + log1pf(expf(-fabsf(x)));
}

// ---------------- W1 fragment image (557056 B, L2-resident) ----------------
// group g = chunk*16 + wv*4 + mf   (chunk = k>>5 in 0..16)
// byte addr = g*2048 + lane*16 + 2*j  (hi), +1024 (lo)
// lane = kq*16 + el holds W[m = wv*64+mf*16+el][k = chunk*32 + kq*8 + j]
__global__ void prep_w1t(const float* __restrict__ W1, u16* __restrict__ ws) {
    const int k = blockIdx.x;          // 0..543
    const int m = threadIdx.x;         // 0..255
    const float v = (k < 519) ? W1[k * 256 + m] : 0.0f;
    const u16 h = f2bf(v);
    const u16 l = f2bf(v - bf2f(h));
    const int kc = k >> 5, kl = k & 31, kq = kl >> 3, j = kl & 7;
    const int wv = m >> 6, mf = (m >> 4) & 3, el = m & 15;
    const int lane = kq * 16 + el;
    const size_t base = (size_t)(kc * 16 + wv * 4 + mf) * 2048 + lane * 16 + j * 2;
    *(u16*)((char*)ws + base) = h;
    *(u16*)((char*)ws + base + 1024) = l;
}

// ---------------- edge kernel ----------------
// 32 edges/block; features per row (1088 B = 544 bf16):
//   z_u [0,256) | z_v [256,512) | abs [512,768) | prod [768,1024) | tail [1024,1088)
// byte col c -> global k = c/2.
#define EF_STRIDE 1088
#define OFF_FH    0        // 34816 B
#define OFF_FL    34816    // 34816 B
#define OFF_SU    69632
#define OFF_SV    69760
#define OFF_SRED  69888    // [4 wv][32 e] float2 = 1024 B
#define LDS_SZ    70912

// 2-bit row key flips byte-bits 4-5; col is a multiple of 16, col^key stays
// inside its 64B block -> bijective per row, in-bounds for all cols <= 1072.
__device__ __forceinline__ int swzE(int e, int col) {
    return e * EF_STRIDE + (col ^ ((e & 3) << 4));
}

__device__ __forceinline__ void split_pair(float x, short8& h8, short8& l8, int j) {
    const u16 hh = f2bf(x);
    h8[j] = (short)hh;
    l8[j] = (short)f2bf(x - bf2f(hh));
}

__global__ __launch_bounds__(256)
void edge_mfma(const float* __restrict__ z,
               const int*   __restrict__ eidx,
               const float* __restrict__ extra,
               const float* __restrict__ b1,
               const float* __restrict__ W2,
               const float* __restrict__ b2,
               const u16*   __restrict__ wimg,
               float* __restrict__ out)
{
    __shared__ alignas(16) char lds[LDS_SZ];
    char* FH = lds + OFF_FH;
    char* FL = lds + OFF_FL;
    int* su = (int*)(lds + OFF_SU);
    int* sv = (int*)(lds + OFF_SV);

    const int t = threadIdx.x, lane = t & 63, wv = t >> 6;
    const int el = lane & 15, kq = lane >> 4;
    const int e0 = blockIdx.x * 32;

    if (t < 32)      su[t] = eidx[e0 + t];
    else if (t < 64) sv[t - 32] = eidx[NEDGES + e0 + (t - 32)];
    __syncthreads();

    // ---- feature build: thread (e = t/8, oct = t%8) owns 16 dims ----
    {
        const int e = t >> 3, oct = t & 7;
        const float* pu = z + (size_t)su[e] * 128 + oct * 16;
        const float* pv = z + (size_t)sv[e] * 128 + oct * 16;
        const f32x4 u0 = *(const f32x4*)(pu),     u1 = *(const f32x4*)(pu + 4);
        const f32x4 u2 = *(const f32x4*)(pu + 8), u3 = *(const f32x4*)(pu + 12);
        const f32x4 v0 = *(const f32x4*)(pv),     v1 = *(const f32x4*)(pv + 4);
        const f32x4 v2 = *(const f32x4*)(pv + 8), v3 = *(const f32x4*)(pv + 12);

        float d = 0.f, nu = 0.f, nv = 0.f;
        #pragma unroll
        for (int j = 0; j < 4; ++j) {
            d  = fmaf(u0[j], v0[j], d);  d  = fmaf(u1[j], v1[j], d);
            d  = fmaf(u2[j], v2[j], d);  d  = fmaf(u3[j], v3[j], d);
            nu = fmaf(u0[j], u0[j], nu); nu = fmaf(u1[j], u1[j], nu);
            nu = fmaf(u2[j], u2[j], nu); nu = fmaf(u3[j], u3[j], nu);
            nv = fmaf(v0[j], v0[j], nv); nv = fmaf(v1[j], v1[j], nv);
            nv = fmaf(v2[j], v2[j], nv); nv = fmaf(v3[j], v3[j], nv);
        }

        #pragma unroll
        for (int half = 0; half < 2; ++half) {
            short8 uh, ul, vh, vl, ah, al, ph, pl;
            #pragma unroll
            for (int j = 0; j < 8; ++j) {
                float uu, vvv;
                if (half == 0) { uu = (j < 4) ? u0[j] : u1[j - 4]; vvv = (j < 4) ? v0[j] : v1[j - 4]; }
                else           { uu = (j < 4) ? u2[j] : u3[j - 4]; vvv = (j < 4) ? v2[j] : v3[j - 4]; }
                split_pair(uu, uh, ul, j);
                split_pair(vvv, vh, vl, j);
                split_pair(fabsf(uu - vvv), ah, al, j);
                split_pair(uu * vvv, ph, pl, j);
            }
            const int c = oct * 32 + half * 16;
            *(short8*)(FH + swzE(e, c)) = uh;          *(short8*)(FL + swzE(e, c)) = ul;
            *(short8*)(FH + swzE(e, 256 + c)) = vh;    *(short8*)(FL + swzE(e, 256 + c)) = vl;
            *(short8*)(FH + swzE(e, 512 + c)) = ah;    *(short8*)(FL + swzE(e, 512 + c)) = al;
            *(short8*)(FH + swzE(e, 768 + c)) = ph;    *(short8*)(FL + swzE(e, 768 + c)) = pl;
        }

        // 8-lane reduce (lanes 8e..8e+7 share edge e)
        d  += __shfl_xor(d, 1);  d  += __shfl_xor(d, 2);  d  += __shfl_xor(d, 4);
        nu += __shfl_xor(nu, 1); nu += __shfl_xor(nu, 2); nu += __shfl_xor(nu, 4);
        nv += __shfl_xor(nv, 1); nv += __shfl_xor(nv, 2); nv += __shfl_xor(nv, 4);

        if (oct == 0) {   // tail: dot, cos, extra[5], 0 at byte col 1024
            const float nn = fmaxf(sqrtf(nu), 1e-12f) * fmaxf(sqrtf(nv), 1e-12f);
            const float* ex = extra + (size_t)(e0 + e) * 5;
            short8 th, tl;
            split_pair(d, th, tl, 0);
            split_pair(d / nn, th, tl, 1);
            split_pair(ex[0], th, tl, 2);
            split_pair(ex[1], th, tl, 3);
            split_pair(ex[2], th, tl, 4);
            split_pair(ex[3], th, tl, 5);
            split_pair(ex[4], th, tl, 6);
            th[7] = 0; tl[7] = 0;
            *(short8*)(FH + swzE(e, 1024)) = th;
            *(short8*)(FL + swzE(e, 1024)) = tl;
        } else if (oct < 4) {   // zero-pad k 520..543 (byte cols 1040/1056/1072)
            const short8 zz = {0, 0, 0, 0, 0, 0, 0, 0};
            const int cz = 1024 + oct * 16;
            *(short8*)(FH + swzE(e, cz)) = zz;
            *(short8*)(FL + swzE(e, cz)) = zz;
        }
    }
    __syncthreads();   // the only barrier before the K loop

    // ---- barrier-free K loop: 17 chunks of 32 k ----
    const f32x4 vz = {0.f, 0.f, 0.f, 0.f};
    f32x4 acc[4][2];
    #pragma unroll
    for (int mf = 0; mf < 4; ++mf) { acc[mf][0] = vz; acc[mf][1] = vz; }

    for (int kc = 0; kc < NCH; ++kc) {
        short8 Bh0, Bl0, Bh1, Bl1;
        {
            const int off = swzE(el, kc * 64 + kq * 16);
            Bh0 = *(const short8*)(FH + off);
            Bl0 = *(const short8*)(FL + off);
        }
        {
            const int off = swzE(16 + el, kc * 64 + kq * 16);
            Bh1 = *(const short8*)(FH + off);
            Bl1 = *(const short8*)(FL + off);
        }
        const char* wch = (const char*)wimg + (size_t)(kc * 16 + wv * 4) * 2048 + lane * 16;
        #pragma unroll
        for (int mf = 0; mf < 4; ++mf) {
            const short8 Ah = *(const short8*)(wch + mf * 2048);
            const short8 Al = *(const short8*)(wch + mf * 2048 + 1024);
            acc[mf][0] = __builtin_amdgcn_mfma_f32_16x16x32_bf16(Ah, Bh0, acc[mf][0], 0, 0, 0);
            acc[mf][0] = __builtin_amdgcn_mfma_f32_16x16x32_bf16(Al, Bh0, acc[mf][0], 0, 0, 0);
            acc[mf][0] = __builtin_amdgcn_mfma_f32_16x16x32_bf16(Ah, Bl0, acc[mf][0], 0, 0, 0);
            acc[mf][1] = __builtin_amdgcn_mfma_f32_16x16x32_bf16(Ah, Bh1, acc[mf][1], 0, 0, 0);
            acc[mf][1] = __builtin_amdgcn_mfma_f32_16x16x32_bf16(Al, Bh1, acc[mf][1], 0, 0, 0);
            acc[mf][1] = __builtin_amdgcn_mfma_f32_16x16x32_bf16(Ah, Bl1, acc[mf][1], 0, 0, 0);
        }
    }

    // ---- epilogue: +b1, ReLU, GEMM2 (256->2), softplus ----
    // D mapping: m = wv*64 + mf*16 + kq*4 + r ; edge = nf*16 + el
    const float bb0 = b2[0], bb1 = b2[1];
    #pragma unroll
    for (int nf = 0; nf < 2; ++nf) {
        float q0 = 0.f, q1 = 0.f;
        #pragma unroll
        for (int mf = 0; mf < 4; ++mf) {
            const int mb = wv * 64 + mf * 16 + kq * 4;
            const f32x4 bv = *(const f32x4*)(b1 + mb);
            #pragma unroll
            for (int r = 0; r < 4; ++r) {
                const float h = fmaxf(acc[mf][nf][r] + bv[r], 0.f);
                q0 = fmaf(h, W2[2 * (mb + r)], q0);
                q1 = fmaf(h, W2[2 * (mb + r) + 1], q1);
            }
        }
        q0 += __shfl_xor(q0, 16); q0 += __shfl_xor(q0, 32);
        q1 += __shfl_xor(q1, 16); q1 += __shfl_xor(q1, 32);
        if (kq == 0)
            *(float2*)(lds + OFF_SRED + (wv * 32 + nf * 16 + el) * 8) = make_float2(q0, q1);
    }
    __syncthreads();
    if (t < 32) {
        float s0 = bb0, s1 = bb1;
        #pragma unroll
        for (int w = 0; w < 4; ++w) {
            const float2 pr = *(const float2*)(lds + OFF_SRED + (w * 32 + t) * 8);
            s0 += pr.x; s1 += pr.y;
        }
        out[2 * (size_t)(e0 + t) + 0] = softplus_f(s0);
        out[2 * (size_t)(e0 + t) + 1] = softplus_f(s1);
    }
}

extern "C" void kernel_launch(void* const* d_in, const int* in_sizes, int n_in,
                              void* d_out, int out_size, void* d_ws, size_t ws_size,
                              hipStream_t stream) {
    const float* zp    = (const float*)d_in[0];
    const int*   eidx  = (const int*)  d_in[1];
    const float* extra = (const float*)d_in[2];
    const float* W1    = (const float*)d_in[3];
    const float* b1    = (const float*)d_in[4];
    const float* W2    = (const float*)d_in[5];
    const float* b2    = (const float*)d_in[6];
    float* out = (float*)d_out;
    u16* wimg = (u16*)d_ws;   // 557056 B only — no other cross-kernel state

    prep_w1t<<<dim3(544), dim3(256), 0, stream>>>(W1, wimg);
    edge_mfma<<<dim3(NEDGES / 32), dim3(256), 0, stream>>>(
        zp, eidx, extra, b1, W2, b2, wimg, out);
}